// Round 4
// baseline (1041.279 us; speedup 1.0000x reference)
//
#include <hip/hip_runtime.h>
#include <math.h>

// Problem constants (fixed by the reference)
#define B_N  16384
#define T_N  3
#define D_N  512
#define G_N  4
#define NE_N 4
#define H_N  512
#define E_N  256
#define GH_N 256
#define K16  16      // G*NE experts
#define TH_N 128
#define TO_N 64

typedef __attribute__((ext_vector_type(8))) short short8;
typedef __attribute__((ext_vector_type(4))) float floatx4;

__device__ __forceinline__ unsigned short f2bf(float f) {
    union { float f; unsigned u; } v; v.f = f;
    unsigned r = (v.u + 0x7fffu + ((v.u >> 16) & 1u)) >> 16;
    return (unsigned short)r;
}
__device__ __forceinline__ float bf2f(unsigned short h) {
    union { unsigned u; float f; } v; v.u = ((unsigned)h) << 16;
    return v.f;
}
__device__ __forceinline__ unsigned pack2(float lo, float hi) {
    return ((unsigned)f2bf(hi) << 16) | (unsigned)f2bf(lo);
}

typedef const __attribute__((address_space(1))) void gvoid_t;
typedef __attribute__((address_space(3))) void lvoid_t;

#if __has_builtin(__builtin_amdgcn_global_load_lds)
#define HAVE_GLL 1
__device__ __forceinline__ void load_lds16(const void* g, void* l) {
    __builtin_amdgcn_global_load_lds((gvoid_t*)g, (lvoid_t*)l, 16, 0, 0);
}
#else
#define HAVE_GLL 0
#endif

// ---------------------------------------------------------------------------
// Input cast: x -> bf16 [BC][G*D]; gin = x[:,1+t]+x[:,0] -> bf16 [BC][T*D]
// ---------------------------------------------------------------------------
__global__ __launch_bounds__(256) void convert_inputs(
    const float* __restrict__ x, unsigned short* __restrict__ xb,
    unsigned short* __restrict__ ginb)
{
    const long b = blockIdx.x;
    const int tid = threadIdx.x;           // 256 threads, 2 floats each per g
    const float* xr = x + b * (G_N * D_N);
    unsigned short* xo = xb + b * (G_N * D_N);
    unsigned short* go = ginb + b * (T_N * D_N);
    float2 v0 = *(const float2*)&xr[tid * 2];
    *(unsigned*)&xo[tid * 2] = pack2(v0.x, v0.y);
    #pragma unroll
    for (int g = 1; g < G_N; ++g) {
        float2 v = *(const float2*)&xr[g * D_N + tid * 2];
        *(unsigned*)&xo[g * D_N + tid * 2] = pack2(v.x, v.y);
        *(unsigned*)&go[(g - 1) * D_N + tid * 2] = pack2(v.x + v0.x, v.y + v0.y);
    }
}

// ---------------------------------------------------------------------------
// Weight transpose + cast: in fp32 [Z][K][N] -> out bf16 [Z][N][K]
// ---------------------------------------------------------------------------
__global__ __launch_bounds__(256) void transpose_w(
    const float* __restrict__ in, unsigned short* __restrict__ out, int K, int N)
{
    __shared__ float tile[32][33];
    const int tx = threadIdx.x, ty = threadIdx.y;      // block (32,8)
    const long zo = (long)blockIdx.z * K * N;
    const int n0 = blockIdx.x * 32, k0 = blockIdx.y * 32;
    #pragma unroll
    for (int i = 0; i < 4; ++i)
        tile[ty + 8 * i][tx] = in[zo + (long)(k0 + ty + 8 * i) * N + n0 + tx];
    __syncthreads();
    #pragma unroll
    for (int i = 0; i < 4; ++i)
        out[zo + (long)(n0 + ty + 8 * i) * K + k0 + tx] = f2bf(tile[tx][ty + 8 * i]);
}

// ---------------------------------------------------------------------------
// bf16 MFMA GEMM: C[z] = act(A[z] (MxK) * Bt[z]^T (N-major NxK) + bias[z])
// 128x128 tile, BK=64, XOR-swizzled LDS (2-way aliasing only, free).
// 256 threads = 4 waves (2x2 of 64x64).  (Used for the gate layer-1 GEMM.)
// ---------------------------------------------------------------------------
template<int RELU>
__global__ __launch_bounds__(256) void gemm_bf16(
    const unsigned short* __restrict__ A, int lda, int a_zoff,
    const unsigned short* __restrict__ Bt, int bt_zoff,
    const float* __restrict__ bias, int bias_zoff,
    unsigned short* __restrict__ C, int ldc, int c_zoff, int K)
{
    __shared__ __align__(16) unsigned short As[2][128 * 32];
    __shared__ __align__(16) unsigned short Bs[2][128 * 32];
    const int tid = threadIdx.x;
    const int z = blockIdx.z;
    const long m0 = (long)blockIdx.x * 128;
    const long n0 = (long)blockIdx.y * 128;
    const unsigned short* Ab = A + (long)z * a_zoff + m0 * lda;
    const unsigned short* Bb = Bt + (long)z * bt_zoff + n0 * K;
    const int lane16 = tid & 15;
    const int quad = (tid & 63) >> 4;
    const int wave = tid >> 6;
    const int wm = (wave >> 1) * 64;
    const int wn = (wave & 1) * 64;
    const int srow = tid >> 2;                       // staging row (0..63)
    const int scolsw = (((tid & 3) ^ ((tid >> 3) & 3)) * 8);  // swizzled col
    const int cw8 = ((quad ^ ((lane16 >> 1) & 3)) * 8);       // frag read col

    floatx4 acc[4][4] = {};

    for (int k0 = 0; k0 < K; k0 += 64) {
        #pragma unroll
        for (int h = 0; h < 2; ++h) {
            const int kh = k0 + h * 32;
#if HAVE_GLL
            load_lds16(Ab + (long)srow * lda + kh + scolsw, &As[h][tid * 8]);
            load_lds16(Ab + (long)(srow + 64) * lda + kh + scolsw, &As[h][2048 + tid * 8]);
            load_lds16(Bb + (long)srow * K + kh + scolsw, &Bs[h][tid * 8]);
            load_lds16(Bb + (long)(srow + 64) * K + kh + scolsw, &Bs[h][2048 + tid * 8]);
#else
            *(uint4*)&As[h][tid * 8] = *(const uint4*)(Ab + (long)srow * lda + kh + scolsw);
            *(uint4*)&As[h][2048 + tid * 8] = *(const uint4*)(Ab + (long)(srow + 64) * lda + kh + scolsw);
            *(uint4*)&Bs[h][tid * 8] = *(const uint4*)(Bb + (long)srow * K + kh + scolsw);
            *(uint4*)&Bs[h][2048 + tid * 8] = *(const uint4*)(Bb + (long)(srow + 64) * K + kh + scolsw);
#endif
        }
        __syncthreads();
        #pragma unroll
        for (int h = 0; h < 2; ++h) {
            short8 a[4], b[4];
            #pragma unroll
            for (int mi = 0; mi < 4; ++mi)
                a[mi] = *(const short8*)&As[h][(wm + mi * 16 + lane16) * 32 + cw8];
            #pragma unroll
            for (int ni = 0; ni < 4; ++ni)
                b[ni] = *(const short8*)&Bs[h][(wn + ni * 16 + lane16) * 32 + cw8];
            #pragma unroll
            for (int mi = 0; mi < 4; ++mi)
                #pragma unroll
                for (int ni = 0; ni < 4; ++ni)
                    acc[mi][ni] = __builtin_amdgcn_mfma_f32_16x16x32_bf16(
                        a[mi], b[ni], acc[mi][ni], 0, 0, 0);
        }
        __syncthreads();
    }

    unsigned short* Cb = C + (long)z * c_zoff + m0 * ldc + n0;
    const float* bb = bias + (long)z * bias_zoff + n0;
    #pragma unroll
    for (int mi = 0; mi < 4; ++mi) {
        #pragma unroll
        for (int ni = 0; ni < 4; ++ni) {
            const int col = wn + ni * 16 + lane16;
            const float bv = bb[col];
            #pragma unroll
            for (int r = 0; r < 4; ++r) {
                const int row = wm + mi * 16 + quad * 4 + r;
                float v = acc[mi][ni][r] + bv;
                if (RELU) v = fmaxf(v, 0.0f);
                Cb[(long)row * ldc + col] = f2bf(v);
            }
        }
    }
}

// ---------------------------------------------------------------------------
// Fused expert MLP v3: per block = 128 rows x 1 expert (v1 structure),
// with staging shrunk to K=32 per barrier-pair (As+Bs = 16 KB) so total
// LDS = 51.2 KB -> 3 blocks/CU (12 waves/CU, the m97 operating point).
// K-blocked fusion over H in 4 chunks of 128; h1 chunk stays in LDS.
// XCD swizzle: expert pair per XCD (bid&7 -> XCD).
// ---------------------------------------------------------------------------
__global__ __launch_bounds__(256, 3) void expert_fused(
    const unsigned short* __restrict__ xb,      // [BC][2048] bf16
    const unsigned short* __restrict__ W1t,     // [16][512][512] bf16 (N-major)
    const float* __restrict__ eb1,              // [16][512]
    const unsigned short* __restrict__ W2t,     // [16][256][512] bf16 (N-major)
    const float* __restrict__ eb2,              // [16][256]
    unsigned short* __restrict__ embb)          // [BC][16*256] bf16
{
    __shared__ __align__(16) unsigned short sm[25600];   // 51200 B
    unsigned short* As  = sm;            // [128*32]  stage-1 A        (8 KB)
    unsigned short* Bs  = sm + 4096;     // [128*32]  stage-1 W1 chunk (8 KB)
    unsigned short* W2s = sm;            // [256*32]  stage-2 W2 (reuses As+Bs)
    unsigned short* h1s = sm + 8192;     // [128][136] h1 chunk        (34 KB)

    const int tid = threadIdx.x;
    const unsigned bid = blockIdx.x;
    // XCD-aware swizzle: bid%8 -> XCD (round-robin dispatch); expert pair per XCD
    const int e = ((bid & 7) << 1) | ((bid >> 3) & 1);
    const long m0 = (long)(bid >> 4) * 128;
    const int g = e >> 2;

    const unsigned short* Ab  = xb + m0 * 2048 + g * 512;    // row stride 2048
    const unsigned short* W1b = W1t + (long)e * (512 * 512);
    const unsigned short* W2b = W2t + (long)e * (256 * 512);

    const int lane16 = tid & 15;
    const int quad = (tid & 63) >> 4;
    const int wave = tid >> 6;
    const int wm  = (wave >> 1) * 64;    // row-block of this wave
    const int wn  = (wave & 1) * 64;     // stage-1 col-block
    const int wn2 = (wave & 1) * 128;    // stage-2 col-block
    const int srow = tid >> 2;
    const int scol = (((tid & 3) ^ ((tid >> 3) & 3)) * 8);   // swizzled col
    const int cw8 = ((quad ^ ((lane16 >> 1) & 3)) * 8);

    floatx4 acc2[4][8] = {};             // emb accumulator (persists all chunks)

    for (int nc = 0; nc < 4; ++nc) {
        const unsigned short* Bb = W1b + ((long)nc << 16);   // nc*128*512
        floatx4 acc[4][4] = {};
        // ---- stage 1: h1c = relu(x @ W1[:, nc*128 : +128]) --------------
        for (int k0 = 0; k0 < 512; k0 += 32) {
#if HAVE_GLL
            load_lds16(Ab + (long)srow * 2048 + k0 + scol, &As[tid * 8]);
            load_lds16(Ab + (long)(srow + 64) * 2048 + k0 + scol, &As[2048 + tid * 8]);
            load_lds16(Bb + (long)srow * 512 + k0 + scol, &Bs[tid * 8]);
            load_lds16(Bb + (long)(srow + 64) * 512 + k0 + scol, &Bs[2048 + tid * 8]);
#else
            *(uint4*)&As[tid * 8] = *(const uint4*)(Ab + (long)srow * 2048 + k0 + scol);
            *(uint4*)&As[2048 + tid * 8] = *(const uint4*)(Ab + (long)(srow + 64) * 2048 + k0 + scol);
            *(uint4*)&Bs[tid * 8] = *(const uint4*)(Bb + (long)srow * 512 + k0 + scol);
            *(uint4*)&Bs[2048 + tid * 8] = *(const uint4*)(Bb + (long)(srow + 64) * 512 + k0 + scol);
#endif
            __syncthreads();
            short8 a[4], b[4];
            #pragma unroll
            for (int mi = 0; mi < 4; ++mi)
                a[mi] = *(const short8*)&As[(wm + mi * 16 + lane16) * 32 + cw8];
            #pragma unroll
            for (int ni = 0; ni < 4; ++ni)
                b[ni] = *(const short8*)&Bs[(wn + ni * 16 + lane16) * 32 + cw8];
            #pragma unroll
            for (int mi = 0; mi < 4; ++mi)
                #pragma unroll
                for (int ni = 0; ni < 4; ++ni)
                    acc[mi][ni] = __builtin_amdgcn_mfma_f32_16x16x32_bf16(
                        a[mi], b[ni], acc[mi][ni], 0, 0, 0);
            __syncthreads();
        }
        // ---- h1 epilogue -> LDS (bf16, stride 136: 2-way banks only) ----
        #pragma unroll
        for (int mi = 0; mi < 4; ++mi) {
            #pragma unroll
            for (int ni = 0; ni < 4; ++ni) {
                const int col = wn + ni * 16 + lane16;
                const float bv = eb1[e * 512 + nc * 128 + col];
                #pragma unroll
                for (int r = 0; r < 4; ++r) {
                    const int row = wm + mi * 16 + quad * 4 + r;
                    h1s[row * 136 + col] = f2bf(fmaxf(acc[mi][ni][r] + bv, 0.0f));
                }
            }
        }
        __syncthreads();
        // ---- stage 2: acc2 += h1c @ W2[nc*128:+128, :] -------------------
        #pragma unroll
        for (int ks = 0; ks < 128; ks += 32) {
            #pragma unroll
            for (int i = 0; i < 4; ++i) {
#if HAVE_GLL
                load_lds16(W2b + (long)(srow + 64 * i) * 512 + nc * 128 + ks + scol,
                           &W2s[i * 2048 + tid * 8]);
#else
                *(uint4*)&W2s[i * 2048 + tid * 8] =
                    *(const uint4*)(W2b + (long)(srow + 64 * i) * 512 + nc * 128 + ks + scol);
#endif
            }
            __syncthreads();
            short8 a2[4];
            #pragma unroll
            for (int mi = 0; mi < 4; ++mi)
                a2[mi] = *(const short8*)&h1s[(wm + mi * 16 + lane16) * 136 + ks + quad * 8];
            #pragma unroll
            for (int nh = 0; nh < 2; ++nh) {
                short8 b2[4];
                #pragma unroll
                for (int nj = 0; nj < 4; ++nj)
                    b2[nj] = *(const short8*)&W2s[(wn2 + nh * 64 + nj * 16 + lane16) * 32 + cw8];
                #pragma unroll
                for (int mi = 0; mi < 4; ++mi)
                    #pragma unroll
                    for (int nj = 0; nj < 4; ++nj)
                        acc2[mi][nh * 4 + nj] = __builtin_amdgcn_mfma_f32_16x16x32_bf16(
                            a2[mi], b2[nj], acc2[mi][nh * 4 + nj], 0, 0, 0);
            }
            __syncthreads();
        }
    }

    // ---- final epilogue: emb -> bf16 embb -------------------------------
    unsigned short* Cb = embb + m0 * 4096 + (long)e * 256;
    #pragma unroll
    for (int mi = 0; mi < 4; ++mi) {
        #pragma unroll
        for (int j = 0; j < 8; ++j) {
            const int col = wn2 + (j >> 2) * 64 + (j & 3) * 16 + lane16;
            const float bv = eb2[e * 256 + col];
            #pragma unroll
            for (int r = 0; r < 4; ++r) {
                const int row = wm + mi * 16 + quad * 4 + r;
                Cb[(long)row * 4096 + col] = f2bf(acc2[mi][j][r] + bv);
            }
        }
    }
}

// ---------------------------------------------------------------------------
// Gate layer 2 + softmax: gw[b][t][k] = softmax_k(gh[b][t]·W2[t] + b2[t])
// ---------------------------------------------------------------------------
__global__ __launch_bounds__(256) void gate2_softmax(
    const unsigned short* __restrict__ gh, const float* __restrict__ W2,
    const float* __restrict__ b2, float* __restrict__ gw)
{
    const int t = blockIdx.y;
    const long b0 = (long)blockIdx.x * 64;
    const int tid = threadIdx.x;
    __shared__ __align__(16) unsigned short ghs[64 * 256];
    __shared__ float ls[64 * 16];
    #pragma unroll
    for (int it = 0; it < 8; ++it) {
        int seg = it * 256 + tid;
        int row = seg >> 5;
        int col = (seg & 31) * 8;
        *(uint4*)&ghs[seg * 8] =
            *(const uint4*)&gh[(b0 + row) * (T_N * GH_N) + (long)t * GH_N + col];
    }
    __syncthreads();
    const float* W2t = W2 + (long)t * GH_N * K16;
    #pragma unroll
    for (int it = 0; it < 4; ++it) {
        int o = it * 256 + tid;
        int b = o >> 4, k = o & 15;
        float acc = b2[t * K16 + k];
        #pragma unroll 8
        for (int h = 0; h < GH_N; ++h)
            acc += bf2f(ghs[b * 256 + h]) * W2t[h * K16 + k];
        ls[o] = acc;
    }
    __syncthreads();
    if (tid < 64) {
        float m = -1e30f;
        #pragma unroll
        for (int k = 0; k < 16; ++k) m = fmaxf(m, ls[tid * 16 + k]);
        float e[16], s = 0.f;
        #pragma unroll
        for (int k = 0; k < 16; ++k) { e[k] = expf(ls[tid * 16 + k] - m); s += e[k]; }
        const float inv = 1.0f / s;
        float* gwp = gw + (b0 + tid) * (T_N * K16) + (long)t * K16;
        #pragma unroll
        for (int k = 0; k < 16; ++k) gwp[k] = e[k] * inv;
    }
}

// ---------------------------------------------------------------------------
// agg: aggb[t][b][e] = bf16( sum_k gw[b][t][k] * emb[b][k*256+e] )
// ---------------------------------------------------------------------------
__global__ __launch_bounds__(256) void agg_kernel(
    const unsigned short* __restrict__ emb, const float* __restrict__ gw,
    unsigned short* __restrict__ aggb, long bc)
{
    const long b = (long)blockIdx.x * 8 + (threadIdx.x >> 5);
    const int e0 = (threadIdx.x & 31) * 8;
    const unsigned short* er = emb + b * 4096 + e0;
    const float* gwr = gw + b * 48;
    float a0[8] = {}, a1[8] = {}, a2[8] = {};
    #pragma unroll
    for (int k = 0; k < 16; ++k) {
        short8 v = *(const short8*)(er + (long)k * 256);
        const float w0 = gwr[k], w1 = gwr[16 + k], w2 = gwr[32 + k];
        #pragma unroll
        for (int j = 0; j < 8; ++j) {
            float f = bf2f((unsigned short)v[j]);
            a0[j] += w0 * f; a1[j] += w1 * f; a2[j] += w2 * f;
        }
    }
    unsigned r0[4] = {pack2(a0[0], a0[1]), pack2(a0[2], a0[3]),
                      pack2(a0[4], a0[5]), pack2(a0[6], a0[7])};
    unsigned r1[4] = {pack2(a1[0], a1[1]), pack2(a1[2], a1[3]),
                      pack2(a1[4], a1[5]), pack2(a1[6], a1[7])};
    unsigned r2[4] = {pack2(a2[0], a2[1]), pack2(a2[2], a2[3]),
                      pack2(a2[4], a2[5]), pack2(a2[6], a2[7])};
    *(uint4*)(aggb + 0L * bc * 256 + b * 256 + e0) = *(uint4*)r0;
    *(uint4*)(aggb + 1L * bc * 256 + b * 256 + e0) = *(uint4*)r1;
    *(uint4*)(aggb + 2L * bc * 256 + b * 256 + e0) = *(uint4*)r2;
}

// ---------------------------------------------------------------------------
// tower_fused (per t): th = relu(agg·W1+b1) [MFMA], out = th·W2+b2 [MFMA]
// ---------------------------------------------------------------------------
__global__ __launch_bounds__(256) void tower_fused(
    const unsigned short* __restrict__ aggb, long bc,
    const unsigned short* __restrict__ w1t, const float* __restrict__ tb1,
    const unsigned short* __restrict__ w2t, const float* __restrict__ tb2,
    float* __restrict__ out)
{
    __shared__ __align__(16) unsigned short sm[26112];   // 52224 B
    unsigned short* As  = sm;            // [128*32]   (stage 1 staging)
    unsigned short* Bs  = sm + 4096;     // [128*32]
    unsigned short* th  = sm;            // [128*136]  (reused after stage 1)
    unsigned short* w2s = sm + 17408;    // [64*136]
    const int tid = threadIdx.x;
    const int t = blockIdx.y;
    const long m0 = (long)blockIdx.x * 128;
    const unsigned short* Ab = aggb + (long)t * bc * 256 + m0 * 256;
    const unsigned short* Bb = w1t + (long)t * (TH_N * E_N);
    const int lane16 = tid & 15;
    const int quad = (tid & 63) >> 4;
    const int wave = tid >> 6;
    const int wm = (wave >> 1) * 64;
    const int wn = (wave & 1) * 64;
    const int srow = tid >> 2;
    const int scolsw = (((tid & 3) ^ ((tid >> 3) & 3)) * 8);
    const int cw8 = ((quad ^ ((lane16 >> 1) & 3)) * 8);

    // W2 tile [64][128] bf16 -> padded w2s [64][136]
    #pragma unroll
    for (int i = 0; i < 4; ++i) {
        const int seg = i * 256 + tid;
        const int row = seg >> 4, cb = (seg & 15) * 8;
        *(uint4*)&w2s[row * 136 + cb] =
            *(const uint4*)&w2t[(long)t * (TO_N * TH_N) + (long)row * 128 + cb];
    }

    floatx4 acc[4][4] = {};
    for (int k0 = 0; k0 < 256; k0 += 32) {
#if HAVE_GLL
        load_lds16(Ab + (long)srow * 256 + k0 + scolsw, &As[tid * 8]);
        load_lds16(Ab + (long)(srow + 64) * 256 + k0 + scolsw, &As[2048 + tid * 8]);
        load_lds16(Bb + (long)srow * 256 + k0 + scolsw, &Bs[tid * 8]);
        load_lds16(Bb + (long)(srow + 64) * 256 + k0 + scolsw, &Bs[2048 + tid * 8]);
#else
        *(uint4*)&As[tid * 8] = *(const uint4*)(Ab + (long)srow * 256 + k0 + scolsw);
        *(uint4*)&As[2048 + tid * 8] = *(const uint4*)(Ab + (long)(srow + 64) * 256 + k0 + scolsw);
        *(uint4*)&Bs[tid * 8] = *(const uint4*)(Bb + (long)srow * 256 + k0 + scolsw);
        *(uint4*)&Bs[2048 + tid * 8] = *(const uint4*)(Bb + (long)(srow + 64) * 256 + k0 + scolsw);
#endif
        __syncthreads();
        short8 a[4], b[4];
        #pragma unroll
        for (int mi = 0; mi < 4; ++mi)
            a[mi] = *(const short8*)&As[(wm + mi * 16 + lane16) * 32 + cw8];
        #pragma unroll
        for (int ni = 0; ni < 4; ++ni)
            b[ni] = *(const short8*)&Bs[(wn + ni * 16 + lane16) * 32 + cw8];
        #pragma unroll
        for (int mi = 0; mi < 4; ++mi)
            #pragma unroll
            for (int ni = 0; ni < 4; ++ni)
                acc[mi][ni] = __builtin_amdgcn_mfma_f32_16x16x32_bf16(
                    a[mi], b[ni], acc[mi][ni], 0, 0, 0);
        __syncthreads();
    }

    #pragma unroll
    for (int mi = 0; mi < 4; ++mi) {
        #pragma unroll
        for (int ni = 0; ni < 4; ++ni) {
            const int col = wn + ni * 16 + lane16;
            const float bv = tb1[t * TH_N + col];
            #pragma unroll
            for (int r = 0; r < 4; ++r) {
                const int row = wm + mi * 16 + quad * 4 + r;
                th[row * 136 + col] = f2bf(fmaxf(acc[mi][ni][r] + bv, 0.0f));
            }
        }
    }
    __syncthreads();

    floatx4 acc2[2][4] = {};
    #pragma unroll
    for (int kk = 0; kk < 4; ++kk) {
        short8 a2[2], b2[4];
        #pragma unroll
        for (int mi = 0; mi < 2; ++mi)
            a2[mi] = *(const short8*)&th[(wave * 32 + mi * 16 + lane16) * 136 + kk * 32 + quad * 8];
        #pragma unroll
        for (int ni = 0; ni < 4; ++ni)
            b2[ni] = *(const short8*)&w2s[(ni * 16 + lane16) * 136 + kk * 32 + quad * 8];
        #pragma unroll
        for (int mi = 0; mi < 2; ++mi)
            #pragma unroll
            for (int ni = 0; ni < 4; ++ni)
                acc2[mi][ni] = __builtin_amdgcn_mfma_f32_16x16x32_bf16(
                    a2[mi], b2[ni], acc2[mi][ni], 0, 0, 0);
    }
    #pragma unroll
    for (int mi = 0; mi < 2; ++mi) {
        #pragma unroll
        for (int ni = 0; ni < 4; ++ni) {
            const int col = ni * 16 + lane16;
            const float bv = tb2[t * TO_N + col];
            #pragma unroll
            for (int r = 0; r < 4; ++r) {
                const int row = wave * 32 + mi * 16 + quad * 4 + r;
                out[(m0 + row) * (T_N * TO_N) + t * TO_N + col] = acc2[mi][ni][r] + bv;
            }
        }
    }
}

// ---------------------------------------------------------------------------
extern "C" void kernel_launch(void* const* d_in, const int* in_sizes, int n_in,
                              void* d_out, int out_size, void* d_ws, size_t ws_size,
                              hipStream_t stream)
{
    const float* x   = (const float*)d_in[0];
    const float* eW1 = (const float*)d_in[1];
    const float* eb1 = (const float*)d_in[2];
    const float* eW2 = (const float*)d_in[3];
    const float* eb2 = (const float*)d_in[4];
    const float* gW1 = (const float*)d_in[5];
    const float* gb1 = (const float*)d_in[6];
    const float* gW2 = (const float*)d_in[7];
    const float* gb2 = (const float*)d_in[8];
    const float* tW1 = (const float*)d_in[9];
    const float* tb1 = (const float*)d_in[10];
    const float* tW2 = (const float*)d_in[11];
    const float* tb2 = (const float*)d_in[12];
    float* out = (float*)d_out;

    char* ws = (char*)d_ws;
    // Persistent weight buffers (bf16, transposed): 13,615,104 B total
    unsigned short* W1t  = (unsigned short*)(ws + 0);          // [16][512][512]
    unsigned short* W2t  = (unsigned short*)(ws + 8388608);    // [16][256][512]
    unsigned short* G1t  = (unsigned short*)(ws + 12582912);   // [3][256][512]
    unsigned short* TW1t = (unsigned short*)(ws + 13369344);   // [3][128][256]
    unsigned short* TW2t = (unsigned short*)(ws + 13565952);   // [3][64][128]
    const size_t WFIX = 13615104;

    // Row-chunk sizing: 18,624 B per row of per-chunk buffers.
    long BCo = 0;
    for (long co = 16384; co >= 128; co >>= 1)
        if (WFIX + (size_t)co * 18624 <= ws_size) { BCo = co; break; }
    if (BCo == 0) return;  // workspace too small — fail cleanly

    char* p = ws + WFIX;
    unsigned short* xb   = (unsigned short*)p; p += BCo * 4096;  // [BCo][G*D]
    unsigned short* ginb = (unsigned short*)p; p += BCo * 3072;  // [BCo][T*D]
    unsigned short* embb = (unsigned short*)p; p += BCo * 8192;  // [BCo][16*E]
    unsigned short* gh   = (unsigned short*)p; p += BCo * 1536;  // [BCo][T*GH]
    float*          gw   = (float*)p;          p += BCo * 192;   // [BCo][T][16]
    unsigned short* aggb = (unsigned short*)p;                   // [3][BCo][256]

    // Weight transposes (once per call)
    transpose_w<<<dim3(16, 16, 16), dim3(32, 8), 0, stream>>>(eW1, W1t, 512, 512);
    transpose_w<<<dim3(8, 16, 16), dim3(32, 8), 0, stream>>>(eW2, W2t, 512, 256);
    transpose_w<<<dim3(8, 16, 3), dim3(32, 8), 0, stream>>>(gW1, G1t, 512, 256);
    transpose_w<<<dim3(4, 8, 3), dim3(32, 8), 0, stream>>>(tW1, TW1t, 256, 128);
    transpose_w<<<dim3(2, 4, 3), dim3(32, 8), 0, stream>>>(tW2, TW2t, 128, 64);

    const long n_o = B_N / BCo;
    for (long c = 0; c < n_o; ++c) {
        const float* xc = x + c * BCo * (G_N * D_N);
        float* outc = out + c * BCo * (T_N * TO_N);

        convert_inputs<<<BCo, 256, 0, stream>>>(xc, xb, ginb);
        // gate layer 1: per t: [BCo x 512] @ [512 x 256] -> relu -> gh (bf16)
        gemm_bf16<1><<<dim3(BCo / 128, 2, 3), 256, 0, stream>>>(
            ginb, 1536, 512, G1t, 131072, gb1, 256, gh, 768, 256, 512);
        // gate layer 2 + softmax -> gw (fp32)
        gate2_softmax<<<dim3(BCo / 64, 3), 256, 0, stream>>>(gh, gW2, gb2, gw);
        // fused expert MLP: 128-row x 1-expert blocks, 3 blocks/CU
        expert_fused<<<dim3((BCo / 128) * 16), 256, 0, stream>>>(
            xb, W1t, eb1, W2t, eb2, embb);
        // agg -> aggb bf16 [3][BCo][256]
        agg_kernel<<<BCo / 8, 256, 0, stream>>>(embb, gw, aggb, BCo);
        // towers (MFMA, fused both layers) -> out fp32
        tower_fused<<<dim3(BCo / 128, 3), 256, 0, stream>>>(
            aggb, BCo, TW1t, tb1, TW2t, tb2, outc);
    }
}

// Round 5
// 593.130 us; speedup vs baseline: 1.7556x; 1.7556x over previous
//
#include <hip/hip_runtime.h>
#include <math.h>

// Problem constants (fixed by the reference)
#define B_N  16384
#define T_N  3
#define D_N  512
#define G_N  4
#define NE_N 4
#define H_N  512
#define E_N  256
#define GH_N 256
#define K16  16      // G*NE experts
#define TH_N 128
#define TO_N 64

typedef __attribute__((ext_vector_type(8))) short short8;
typedef __attribute__((ext_vector_type(4))) float floatx4;

__device__ __forceinline__ unsigned short f2bf(float f) {
    union { float f; unsigned u; } v; v.f = f;
    unsigned r = (v.u + 0x7fffu + ((v.u >> 16) & 1u)) >> 16;
    return (unsigned short)r;
}
__device__ __forceinline__ float bf2f(unsigned short h) {
    union { unsigned u; float f; } v; v.u = ((unsigned)h) << 16;
    return v.f;
}
__device__ __forceinline__ unsigned pack2(float lo, float hi) {
    return ((unsigned)f2bf(hi) << 16) | (unsigned)f2bf(lo);
}

typedef const __attribute__((address_space(1))) void gvoid_t;
typedef __attribute__((address_space(3))) void lvoid_t;

#if __has_builtin(__builtin_amdgcn_global_load_lds)
#define HAVE_GLL 1
__device__ __forceinline__ void load_lds16(const void* g, void* l) {
    __builtin_amdgcn_global_load_lds((gvoid_t*)g, (lvoid_t*)l, 16, 0, 0);
}
#else
#define HAVE_GLL 0
#endif

// ---------------------------------------------------------------------------
// Input cast: x -> bf16 [BC][G*D]; gin = x[:,1+t]+x[:,0] -> bf16 [BC][T*D]
// (standalone version, used only when the batch is chunked: n_o > 1)
// ---------------------------------------------------------------------------
__global__ __launch_bounds__(256) void convert_inputs(
    const float* __restrict__ x, unsigned short* __restrict__ xb,
    unsigned short* __restrict__ ginb)
{
    const long b = blockIdx.x;
    const int tid = threadIdx.x;           // 256 threads, 2 floats each per g
    const float* xr = x + b * (G_N * D_N);
    unsigned short* xo = xb + b * (G_N * D_N);
    unsigned short* go = ginb + b * (T_N * D_N);
    float2 v0 = *(const float2*)&xr[tid * 2];
    *(unsigned*)&xo[tid * 2] = pack2(v0.x, v0.y);
    #pragma unroll
    for (int g = 1; g < G_N; ++g) {
        float2 v = *(const float2*)&xr[g * D_N + tid * 2];
        *(unsigned*)&xo[g * D_N + tid * 2] = pack2(v.x, v.y);
        *(unsigned*)&go[(g - 1) * D_N + tid * 2] = pack2(v.x + v0.x, v.y + v0.y);
    }
}

// ---------------------------------------------------------------------------
// prep_kernel: ALL weight transposes (5 matrices, 6648 tiles) + input convert
// (nconv rows) in ONE launch.  1-D grid, segment decoded from blockIdx.x:
//   [0,4096)      eW1  [16][512][512] -> W1t   (16x16 tiles x 16 z)
//   [4096,6144)   eW2  [16][512][256] -> W2t   (8x16 x 16)
//   [6144,6528)   gW1  [3][512][256]  -> G1t   (8x16 x 3)
//   [6528,6624)   tW1  [3][256][128]  -> TW1t  (4x8 x 3)
//   [6624,6648)   tW2  [3][128][64]   -> TW2t  (2x4 x 3)
//   [6648,6648+nconv)  convert row (bid-6648)
// Tile body identical to the previous transpose_w; convert body identical to
// convert_inputs.  Divergence is block-uniform.
// ---------------------------------------------------------------------------
__global__ __launch_bounds__(256) void prep_kernel(
    const float* __restrict__ eW1, const float* __restrict__ eW2,
    const float* __restrict__ gW1, const float* __restrict__ tW1,
    const float* __restrict__ tW2,
    unsigned short* __restrict__ W1t, unsigned short* __restrict__ W2t,
    unsigned short* __restrict__ G1t, unsigned short* __restrict__ TW1t,
    unsigned short* __restrict__ TW2t,
    const float* __restrict__ x, unsigned short* __restrict__ xb,
    unsigned short* __restrict__ ginb)
{
    const int bid = blockIdx.x;
    if (bid < 6648) {
        const float* in; unsigned short* out; int K, N, nx, local;
        if (bid < 4096)      { in = eW1; out = W1t;  K = 512; N = 512; nx = 16; local = bid; }
        else if (bid < 6144) { in = eW2; out = W2t;  K = 512; N = 256; nx = 8;  local = bid - 4096; }
        else if (bid < 6528) { in = gW1; out = G1t;  K = 512; N = 256; nx = 8;  local = bid - 6144; }
        else if (bid < 6624) { in = tW1; out = TW1t; K = 256; N = 128; nx = 4;  local = bid - 6528; }
        else                 { in = tW2; out = TW2t; K = 128; N = 64;  nx = 2;  local = bid - 6624; }
        const int ny = K / 32;
        const int xt = local % nx;
        const int yt = (local / nx) % ny;
        const int z  = local / (nx * ny);
        __shared__ float tile[32][33];
        const int tx = threadIdx.x & 31, ty = threadIdx.x >> 5;   // (32,8)
        const long zo = (long)z * K * N;
        const int n0 = xt * 32, k0 = yt * 32;
        #pragma unroll
        for (int i = 0; i < 4; ++i)
            tile[ty + 8 * i][tx] = in[zo + (long)(k0 + ty + 8 * i) * N + n0 + tx];
        __syncthreads();
        #pragma unroll
        for (int i = 0; i < 4; ++i)
            out[zo + (long)(n0 + ty + 8 * i) * K + k0 + tx] = f2bf(tile[tx][ty + 8 * i]);
    } else {
        const long b = bid - 6648;
        const int tid = threadIdx.x;
        const float* xr = x + b * (G_N * D_N);
        unsigned short* xo = xb + b * (G_N * D_N);
        unsigned short* go = ginb + b * (T_N * D_N);
        float2 v0 = *(const float2*)&xr[tid * 2];
        *(unsigned*)&xo[tid * 2] = pack2(v0.x, v0.y);
        #pragma unroll
        for (int g = 1; g < G_N; ++g) {
            float2 v = *(const float2*)&xr[g * D_N + tid * 2];
            *(unsigned*)&xo[g * D_N + tid * 2] = pack2(v.x, v.y);
            *(unsigned*)&go[(g - 1) * D_N + tid * 2] = pack2(v.x + v0.x, v.y + v0.y);
        }
    }
}

// ---------------------------------------------------------------------------
// bf16 MFMA GEMM: C[z] = act(A[z] (MxK) * Bt[z]^T (N-major NxK) + bias[z])
// 128x128 tile, BK=64, XOR-swizzled LDS (2-way aliasing only, free).
// 256 threads = 4 waves (2x2 of 64x64).  (Used for the gate layer-1 GEMM.)
// ---------------------------------------------------------------------------
template<int RELU>
__global__ __launch_bounds__(256) void gemm_bf16(
    const unsigned short* __restrict__ A, int lda, int a_zoff,
    const unsigned short* __restrict__ Bt, int bt_zoff,
    const float* __restrict__ bias, int bias_zoff,
    unsigned short* __restrict__ C, int ldc, int c_zoff, int K)
{
    __shared__ __align__(16) unsigned short As[2][128 * 32];
    __shared__ __align__(16) unsigned short Bs[2][128 * 32];
    const int tid = threadIdx.x;
    const int z = blockIdx.z;
    const long m0 = (long)blockIdx.x * 128;
    const long n0 = (long)blockIdx.y * 128;
    const unsigned short* Ab = A + (long)z * a_zoff + m0 * lda;
    const unsigned short* Bb = Bt + (long)z * bt_zoff + n0 * K;
    const int lane16 = tid & 15;
    const int quad = (tid & 63) >> 4;
    const int wave = tid >> 6;
    const int wm = (wave >> 1) * 64;
    const int wn = (wave & 1) * 64;
    const int srow = tid >> 2;                       // staging row (0..63)
    const int scolsw = (((tid & 3) ^ ((tid >> 3) & 3)) * 8);  // swizzled col
    const int cw8 = ((quad ^ ((lane16 >> 1) & 3)) * 8);       // frag read col

    floatx4 acc[4][4] = {};

    for (int k0 = 0; k0 < K; k0 += 64) {
        #pragma unroll
        for (int h = 0; h < 2; ++h) {
            const int kh = k0 + h * 32;
#if HAVE_GLL
            load_lds16(Ab + (long)srow * lda + kh + scolsw, &As[h][tid * 8]);
            load_lds16(Ab + (long)(srow + 64) * lda + kh + scolsw, &As[h][2048 + tid * 8]);
            load_lds16(Bb + (long)srow * K + kh + scolsw, &Bs[h][tid * 8]);
            load_lds16(Bb + (long)(srow + 64) * K + kh + scolsw, &Bs[h][2048 + tid * 8]);
#else
            *(uint4*)&As[h][tid * 8] = *(const uint4*)(Ab + (long)srow * lda + kh + scolsw);
            *(uint4*)&As[h][2048 + tid * 8] = *(const uint4*)(Ab + (long)(srow + 64) * lda + kh + scolsw);
            *(uint4*)&Bs[h][tid * 8] = *(const uint4*)(Bb + (long)srow * K + kh + scolsw);
            *(uint4*)&Bs[h][2048 + tid * 8] = *(const uint4*)(Bb + (long)(srow + 64) * K + kh + scolsw);
#endif
        }
        __syncthreads();
        #pragma unroll
        for (int h = 0; h < 2; ++h) {
            short8 a[4], b[4];
            #pragma unroll
            for (int mi = 0; mi < 4; ++mi)
                a[mi] = *(const short8*)&As[h][(wm + mi * 16 + lane16) * 32 + cw8];
            #pragma unroll
            for (int ni = 0; ni < 4; ++ni)
                b[ni] = *(const short8*)&Bs[h][(wn + ni * 16 + lane16) * 32 + cw8];
            #pragma unroll
            for (int mi = 0; mi < 4; ++mi)
                #pragma unroll
                for (int ni = 0; ni < 4; ++ni)
                    acc[mi][ni] = __builtin_amdgcn_mfma_f32_16x16x32_bf16(
                        a[mi], b[ni], acc[mi][ni], 0, 0, 0);
        }
        __syncthreads();
    }

    unsigned short* Cb = C + (long)z * c_zoff + m0 * ldc + n0;
    const float* bb = bias + (long)z * bias_zoff + n0;
    #pragma unroll
    for (int mi = 0; mi < 4; ++mi) {
        #pragma unroll
        for (int ni = 0; ni < 4; ++ni) {
            const int col = wn + ni * 16 + lane16;
            const float bv = bb[col];
            #pragma unroll
            for (int r = 0; r < 4; ++r) {
                const int row = wm + mi * 16 + quad * 4 + r;
                float v = acc[mi][ni][r] + bv;
                if (RELU) v = fmaxf(v, 0.0f);
                Cb[(long)row * ldc + col] = f2bf(v);
            }
        }
    }
}

// ---------------------------------------------------------------------------
// Fused expert MLP (v1, harness-verified @276us): per block = 128 rows x 1
// expert e.  emb[rows,0:256] = relu(x_g @ W1_e) @ W2_e + b2, K-blocked over H
// in 4 chunks of 128; h1 chunk stays in LDS (never touches HBM).
// LDS: 32 KB staging + 34.8 KB h1 = 67.6 KB (2 blocks/CU).  Register floor
// acc2(128 f32)+acc(64 f32) pins this kernel at 2 waves/SIMD — do NOT raise
// the launch_bounds occupancy arg (round-4: (256,3) spilled accs to scratch,
// WRITE 131MB->1.16GB, 276->713us).
// XCD swizzle: experts {2j,2j+1} pinned to XCD j; weight set 1.5 MB/XCD
// stays L2-resident.
// ---------------------------------------------------------------------------
__global__ __launch_bounds__(256, 2) void expert_fused(
    const unsigned short* __restrict__ xb,      // [BC][2048] bf16
    const unsigned short* __restrict__ W1t,     // [16][512][512] bf16 (N-major)
    const float* __restrict__ eb1,              // [16][512]
    const unsigned short* __restrict__ W2t,     // [16][256][512] bf16 (N-major)
    const float* __restrict__ eb2,              // [16][256]
    unsigned short* __restrict__ embb)          // [BC][16*256] bf16
{
    __shared__ __align__(16) unsigned short sm[33792];   // 67584 B
    unsigned short* As  = sm;            // [2][4096]  (stage-1 A / stage-2 W2 tile)
    unsigned short* Bs  = sm + 8192;     // [2][4096]  (stage-1 W1 tile)
    unsigned short* h1s = sm + 16384;    // [128][136] (h1 chunk, padded)

    const int tid = threadIdx.x;
    const unsigned bid = blockIdx.x;
    // XCD-aware swizzle: bid%8 -> XCD (round-robin dispatch); expert pair per XCD
    const int e = ((bid & 7) << 1) | ((bid >> 3) & 1);
    const long m0 = (long)(bid >> 4) * 128;
    const int g = e >> 2;

    const unsigned short* Ab  = xb + m0 * 2048 + g * 512;    // row stride 2048
    const unsigned short* W1b = W1t + (long)e * (512 * 512);
    const unsigned short* W2b = W2t + (long)e * (256 * 512);

    const int lane16 = tid & 15;
    const int quad = (tid & 63) >> 4;
    const int wave = tid >> 6;
    const int wm  = (wave >> 1) * 64;    // row-block of this wave
    const int wn  = (wave & 1) * 64;     // stage-1 col-block
    const int wn2 = (wave & 1) * 128;    // stage-2 col-block
    const int srow = tid >> 2;
    const int scolsw = (((tid & 3) ^ ((tid >> 3) & 3)) * 8);
    const int cw8 = ((quad ^ ((lane16 >> 1) & 3)) * 8);

    floatx4 acc2[4][8] = {};             // emb accumulator (persists all chunks)

    for (int nc = 0; nc < 4; ++nc) {
        const unsigned short* Bb = W1b + ((long)nc << 16);   // nc*128*512
        floatx4 acc[4][4] = {};
        // ---- stage 1: h1c = relu(x @ W1[:, nc*128 : +128]) --------------
        for (int k0 = 0; k0 < 512; k0 += 64) {
            #pragma unroll
            for (int h = 0; h < 2; ++h) {
                const int kh = k0 + h * 32;
#if HAVE_GLL
                load_lds16(Ab + (long)srow * 2048 + kh + scolsw, &As[h * 4096 + tid * 8]);
                load_lds16(Ab + (long)(srow + 64) * 2048 + kh + scolsw, &As[h * 4096 + 2048 + tid * 8]);
                load_lds16(Bb + (long)srow * 512 + kh + scolsw, &Bs[h * 4096 + tid * 8]);
                load_lds16(Bb + (long)(srow + 64) * 512 + kh + scolsw, &Bs[h * 4096 + 2048 + tid * 8]);
#else
                *(uint4*)&As[h * 4096 + tid * 8] = *(const uint4*)(Ab + (long)srow * 2048 + kh + scolsw);
                *(uint4*)&As[h * 4096 + 2048 + tid * 8] = *(const uint4*)(Ab + (long)(srow + 64) * 2048 + kh + scolsw);
                *(uint4*)&Bs[h * 4096 + tid * 8] = *(const uint4*)(Bb + (long)srow * 512 + kh + scolsw);
                *(uint4*)&Bs[h * 4096 + 2048 + tid * 8] = *(const uint4*)(Bb + (long)(srow + 64) * 512 + kh + scolsw);
#endif
            }
            __syncthreads();
            #pragma unroll
            for (int h = 0; h < 2; ++h) {
                short8 b[4];
                #pragma unroll
                for (int ni = 0; ni < 4; ++ni)
                    b[ni] = *(const short8*)&Bs[h * 4096 + (wn + ni * 16 + lane16) * 32 + cw8];
                #pragma unroll
                for (int mi = 0; mi < 4; ++mi) {
                    short8 a = *(const short8*)&As[h * 4096 + (wm + mi * 16 + lane16) * 32 + cw8];
                    #pragma unroll
                    for (int ni = 0; ni < 4; ++ni)
                        acc[mi][ni] = __builtin_amdgcn_mfma_f32_16x16x32_bf16(
                            a, b[ni], acc[mi][ni], 0, 0, 0);
                }
            }
            __syncthreads();
        }
        // ---- h1 epilogue -> LDS (bf16, stride 136: 2-way banks only) ----
        #pragma unroll
        for (int mi = 0; mi < 4; ++mi) {
            #pragma unroll
            for (int ni = 0; ni < 4; ++ni) {
                const int col = wn + ni * 16 + lane16;
                const float bv = eb1[e * 512 + nc * 128 + col];
                #pragma unroll
                for (int r = 0; r < 4; ++r) {
                    const int row = wm + mi * 16 + quad * 4 + r;
                    h1s[row * 136 + col] = f2bf(fmaxf(acc[mi][ni][r] + bv, 0.0f));
                }
            }
        }
        __syncthreads();
        // ---- stage 2: acc2 += h1c @ W2[nc*128:+128, :] -------------------
        #pragma unroll
        for (int ks = 0; ks < 128; ks += 32) {
            #pragma unroll
            for (int i = 0; i < 4; ++i) {
#if HAVE_GLL
                load_lds16(W2b + (long)(srow + 64 * i) * 512 + nc * 128 + ks + scolsw,
                           &As[i * 2048 + tid * 8]);
#else
                *(uint4*)&As[i * 2048 + tid * 8] =
                    *(const uint4*)(W2b + (long)(srow + 64 * i) * 512 + nc * 128 + ks + scolsw);
#endif
            }
            __syncthreads();
            #pragma unroll
            for (int nh = 0; nh < 2; ++nh) {
                short8 b2[4];
                #pragma unroll
                for (int nj = 0; nj < 4; ++nj)
                    b2[nj] = *(const short8*)&As[(wn2 + nh * 64 + nj * 16 + lane16) * 32 + cw8];
                #pragma unroll
                for (int mi = 0; mi < 4; ++mi) {
                    short8 a2 = *(const short8*)&h1s[(wm + mi * 16 + lane16) * 136 + ks + quad * 8];
                    #pragma unroll
                    for (int nj = 0; nj < 4; ++nj)
                        acc2[mi][nh * 4 + nj] = __builtin_amdgcn_mfma_f32_16x16x32_bf16(
                            a2, b2[nj], acc2[mi][nh * 4 + nj], 0, 0, 0);
                }
            }
            __syncthreads();
        }
    }

    // ---- final epilogue: emb -> bf16 embb -------------------------------
    unsigned short* Cb = embb + m0 * 4096 + (long)e * 256;
    #pragma unroll
    for (int mi = 0; mi < 4; ++mi) {
        #pragma unroll
        for (int j = 0; j < 8; ++j) {
            const int col = wn2 + (j >> 2) * 64 + (j & 3) * 16 + lane16;
            const float bv = eb2[e * 256 + col];
            #pragma unroll
            for (int r = 0; r < 4; ++r) {
                const int row = wm + mi * 16 + quad * 4 + r;
                Cb[(long)row * 4096 + col] = f2bf(acc2[mi][j][r] + bv);
            }
        }
    }
}

// ---------------------------------------------------------------------------
// Gate layer 2 + softmax: gw[b][t][k] = softmax_k(gh[b][t]·W2[t] + b2[t])
// ---------------------------------------------------------------------------
__global__ __launch_bounds__(256) void gate2_softmax(
    const unsigned short* __restrict__ gh, const float* __restrict__ W2,
    const float* __restrict__ b2, float* __restrict__ gw)
{
    const int t = blockIdx.y;
    const long b0 = (long)blockIdx.x * 64;
    const int tid = threadIdx.x;
    __shared__ __align__(16) unsigned short ghs[64 * 256];
    __shared__ float ls[64 * 16];
    #pragma unroll
    for (int it = 0; it < 8; ++it) {
        int seg = it * 256 + tid;
        int row = seg >> 5;
        int col = (seg & 31) * 8;
        *(uint4*)&ghs[seg * 8] =
            *(const uint4*)&gh[(b0 + row) * (T_N * GH_N) + (long)t * GH_N + col];
    }
    __syncthreads();
    const float* W2t = W2 + (long)t * GH_N * K16;
    #pragma unroll
    for (int it = 0; it < 4; ++it) {
        int o = it * 256 + tid;
        int b = o >> 4, k = o & 15;
        float acc = b2[t * K16 + k];
        #pragma unroll 8
        for (int h = 0; h < GH_N; ++h)
            acc += bf2f(ghs[b * 256 + h]) * W2t[h * K16 + k];
        ls[o] = acc;
    }
    __syncthreads();
    if (tid < 64) {
        float m = -1e30f;
        #pragma unroll
        for (int k = 0; k < 16; ++k) m = fmaxf(m, ls[tid * 16 + k]);
        float e[16], s = 0.f;
        #pragma unroll
        for (int k = 0; k < 16; ++k) { e[k] = expf(ls[tid * 16 + k] - m); s += e[k]; }
        const float inv = 1.0f / s;
        float* gwp = gw + (b0 + tid) * (T_N * K16) + (long)t * K16;
        #pragma unroll
        for (int k = 0; k < 16; ++k) gwp[k] = e[k] * inv;
    }
}

// ---------------------------------------------------------------------------
// agg: aggb[t][b][e] = bf16( sum_k gw[b][t][k] * emb[b][k*256+e] )
// ---------------------------------------------------------------------------
__global__ __launch_bounds__(256) void agg_kernel(
    const unsigned short* __restrict__ emb, const float* __restrict__ gw,
    unsigned short* __restrict__ aggb, long bc)
{
    const long b = (long)blockIdx.x * 8 + (threadIdx.x >> 5);
    const int e0 = (threadIdx.x & 31) * 8;
    const unsigned short* er = emb + b * 4096 + e0;
    const float* gwr = gw + b * 48;
    float a0[8] = {}, a1[8] = {}, a2[8] = {};
    #pragma unroll
    for (int k = 0; k < 16; ++k) {
        short8 v = *(const short8*)(er + (long)k * 256);
        const float w0 = gwr[k], w1 = gwr[16 + k], w2 = gwr[32 + k];
        #pragma unroll
        for (int j = 0; j < 8; ++j) {
            float f = bf2f((unsigned short)v[j]);
            a0[j] += w0 * f; a1[j] += w1 * f; a2[j] += w2 * f;
        }
    }
    unsigned r0[4] = {pack2(a0[0], a0[1]), pack2(a0[2], a0[3]),
                      pack2(a0[4], a0[5]), pack2(a0[6], a0[7])};
    unsigned r1[4] = {pack2(a1[0], a1[1]), pack2(a1[2], a1[3]),
                      pack2(a1[4], a1[5]), pack2(a1[6], a1[7])};
    unsigned r2[4] = {pack2(a2[0], a2[1]), pack2(a2[2], a2[3]),
                      pack2(a2[4], a2[5]), pack2(a2[6], a2[7])};
    *(uint4*)(aggb + 0L * bc * 256 + b * 256 + e0) = *(uint4*)r0;
    *(uint4*)(aggb + 1L * bc * 256 + b * 256 + e0) = *(uint4*)r1;
    *(uint4*)(aggb + 2L * bc * 256 + b * 256 + e0) = *(uint4*)r2;
}

// ---------------------------------------------------------------------------
// tower_fused (per t): th = relu(agg·W1+b1) [MFMA], out = th·W2+b2 [MFMA]
// ---------------------------------------------------------------------------
__global__ __launch_bounds__(256) void tower_fused(
    const unsigned short* __restrict__ aggb, long bc,
    const unsigned short* __restrict__ w1t, const float* __restrict__ tb1,
    const unsigned short* __restrict__ w2t, const float* __restrict__ tb2,
    float* __restrict__ out)
{
    __shared__ __align__(16) unsigned short sm[26112];   // 52224 B
    unsigned short* As  = sm;            // [128*32]   (stage 1 staging)
    unsigned short* Bs  = sm + 4096;     // [128*32]
    unsigned short* th  = sm;            // [128*136]  (reused after stage 1)
    unsigned short* w2s = sm + 17408;    // [64*136]
    const int tid = threadIdx.x;
    const int t = blockIdx.y;
    const long m0 = (long)blockIdx.x * 128;
    const unsigned short* Ab = aggb + (long)t * bc * 256 + m0 * 256;
    const unsigned short* Bb = w1t + (long)t * (TH_N * E_N);
    const int lane16 = tid & 15;
    const int quad = (tid & 63) >> 4;
    const int wave = tid >> 6;
    const int wm = (wave >> 1) * 64;
    const int wn = (wave & 1) * 64;
    const int srow = tid >> 2;
    const int scolsw = (((tid & 3) ^ ((tid >> 3) & 3)) * 8);
    const int cw8 = ((quad ^ ((lane16 >> 1) & 3)) * 8);

    // W2 tile [64][128] bf16 -> padded w2s [64][136]
    #pragma unroll
    for (int i = 0; i < 4; ++i) {
        const int seg = i * 256 + tid;
        const int row = seg >> 4, cb = (seg & 15) * 8;
        *(uint4*)&w2s[row * 136 + cb] =
            *(const uint4*)&w2t[(long)t * (TO_N * TH_N) + (long)row * 128 + cb];
    }

    floatx4 acc[4][4] = {};
    for (int k0 = 0; k0 < 256; k0 += 32) {
#if HAVE_GLL
        load_lds16(Ab + (long)srow * 256 + k0 + scolsw, &As[tid * 8]);
        load_lds16(Ab + (long)(srow + 64) * 256 + k0 + scolsw, &As[2048 + tid * 8]);
        load_lds16(Bb + (long)srow * 256 + k0 + scolsw, &Bs[tid * 8]);
        load_lds16(Bb + (long)(srow + 64) * 256 + k0 + scolsw, &Bs[2048 + tid * 8]);
#else
        *(uint4*)&As[tid * 8] = *(const uint4*)(Ab + (long)srow * 256 + k0 + scolsw);
        *(uint4*)&As[2048 + tid * 8] = *(const uint4*)(Ab + (long)(srow + 64) * 256 + k0 + scolsw);
        *(uint4*)&Bs[tid * 8] = *(const uint4*)(Bb + (long)srow * 256 + k0 + scolsw);
        *(uint4*)&Bs[2048 + tid * 8] = *(const uint4*)(Bb + (long)(srow + 64) * 256 + k0 + scolsw);
#endif
        __syncthreads();
        short8 a[4], b[4];
        #pragma unroll
        for (int mi = 0; mi < 4; ++mi)
            a[mi] = *(const short8*)&As[(wm + mi * 16 + lane16) * 32 + cw8];
        #pragma unroll
        for (int ni = 0; ni < 4; ++ni)
            b[ni] = *(const short8*)&Bs[(wn + ni * 16 + lane16) * 32 + cw8];
        #pragma unroll
        for (int mi = 0; mi < 4; ++mi)
            #pragma unroll
            for (int ni = 0; ni < 4; ++ni)
                acc[mi][ni] = __builtin_amdgcn_mfma_f32_16x16x32_bf16(
                    a[mi], b[ni], acc[mi][ni], 0, 0, 0);
        __syncthreads();
    }

    #pragma unroll
    for (int mi = 0; mi < 4; ++mi) {
        #pragma unroll
        for (int ni = 0; ni < 4; ++ni) {
            const int col = wn + ni * 16 + lane16;
            const float bv = tb1[t * TH_N + col];
            #pragma unroll
            for (int r = 0; r < 4; ++r) {
                const int row = wm + mi * 16 + quad * 4 + r;
                th[row * 136 + col] = f2bf(fmaxf(acc[mi][ni][r] + bv, 0.0f));
            }
        }
    }
    __syncthreads();

    floatx4 acc2[2][4] = {};
    #pragma unroll
    for (int kk = 0; kk < 4; ++kk) {
        short8 a2[2], b2[4];
        #pragma unroll
        for (int mi = 0; mi < 2; ++mi)
            a2[mi] = *(const short8*)&th[(wave * 32 + mi * 16 + lane16) * 136 + kk * 32 + quad * 8];
        #pragma unroll
        for (int ni = 0; ni < 4; ++ni)
            b2[ni] = *(const short8*)&w2s[(ni * 16 + lane16) * 136 + kk * 32 + quad * 8];
        #pragma unroll
        for (int mi = 0; mi < 2; ++mi)
            #pragma unroll
            for (int ni = 0; ni < 4; ++ni)
                acc2[mi][ni] = __builtin_amdgcn_mfma_f32_16x16x32_bf16(
                    a2[mi], b2[ni], acc2[mi][ni], 0, 0, 0);
    }
    #pragma unroll
    for (int mi = 0; mi < 2; ++mi) {
        #pragma unroll
        for (int ni = 0; ni < 4; ++ni) {
            const int col = ni * 16 + lane16;
            const float bv = tb2[t * TO_N + col];
            #pragma unroll
            for (int r = 0; r < 4; ++r) {
                const int row = wave * 32 + mi * 16 + quad * 4 + r;
                out[(m0 + row) * (T_N * TO_N) + t * TO_N + col] = acc2[mi][ni][r] + bv;
            }
        }
    }
}

// ---------------------------------------------------------------------------
extern "C" void kernel_launch(void* const* d_in, const int* in_sizes, int n_in,
                              void* d_out, int out_size, void* d_ws, size_t ws_size,
                              hipStream_t stream)
{
    const float* x   = (const float*)d_in[0];
    const float* eW1 = (const float*)d_in[1];
    const float* eb1 = (const float*)d_in[2];
    const float* eW2 = (const float*)d_in[3];
    const float* eb2 = (const float*)d_in[4];
    const float* gW1 = (const float*)d_in[5];
    const float* gb1 = (const float*)d_in[6];
    const float* gW2 = (const float*)d_in[7];
    const float* gb2 = (const float*)d_in[8];
    const float* tW1 = (const float*)d_in[9];
    const float* tb1 = (const float*)d_in[10];
    const float* tW2 = (const float*)d_in[11];
    const float* tb2 = (const float*)d_in[12];
    float* out = (float*)d_out;

    char* ws = (char*)d_ws;
    // Persistent weight buffers (bf16, transposed): 13,615,104 B total
    unsigned short* W1t  = (unsigned short*)(ws + 0);          // [16][512][512]
    unsigned short* W2t  = (unsigned short*)(ws + 8388608);    // [16][256][512]
    unsigned short* G1t  = (unsigned short*)(ws + 12582912);   // [3][256][512]
    unsigned short* TW1t = (unsigned short*)(ws + 13369344);   // [3][128][256]
    unsigned short* TW2t = (unsigned short*)(ws + 13565952);   // [3][64][128]
    const size_t WFIX = 13615104;

    // Row-chunk sizing: 18,624 B per row of per-chunk buffers.
    long BCo = 0;
    for (long co = 16384; co >= 128; co >>= 1)
        if (WFIX + (size_t)co * 18624 <= ws_size) { BCo = co; break; }
    if (BCo == 0) return;  // workspace too small — fail cleanly

    char* p = ws + WFIX;
    unsigned short* xb   = (unsigned short*)p; p += BCo * 4096;  // [BCo][G*D]
    unsigned short* ginb = (unsigned short*)p; p += BCo * 3072;  // [BCo][T*D]
    unsigned short* embb = (unsigned short*)p; p += BCo * 8192;  // [BCo][16*E]
    unsigned short* gh   = (unsigned short*)p; p += BCo * 1536;  // [BCo][T*GH]
    float*          gw   = (float*)p;          p += BCo * 192;   // [BCo][T][16]
    unsigned short* aggb = (unsigned short*)p;                   // [3][BCo][256]

    const long n_o = B_N / BCo;

    // One launch: all 5 weight transposes (+ input convert when unchunked)
    const long nconv = (n_o == 1) ? BCo : 0;
    prep_kernel<<<dim3((unsigned)(6648 + nconv)), 256, 0, stream>>>(
        eW1, eW2, gW1, tW1, tW2, W1t, W2t, G1t, TW1t, TW2t, x, xb, ginb);

    for (long c = 0; c < n_o; ++c) {
        const float* xc = x + c * BCo * (G_N * D_N);
        float* outc = out + c * BCo * (T_N * TO_N);

        if (n_o > 1)
            convert_inputs<<<BCo, 256, 0, stream>>>(xc, xb, ginb);
        // gate layer 1: per t: [BCo x 512] @ [512 x 256] -> relu -> gh (bf16)
        gemm_bf16<1><<<dim3(BCo / 128, 2, 3), 256, 0, stream>>>(
            ginb, 1536, 512, G1t, 131072, gb1, 256, gh, 768, 256, 512);
        // gate layer 2 + softmax -> gw (fp32)
        gate2_softmax<<<dim3(BCo / 64, 3), 256, 0, stream>>>(gh, gW2, gb2, gw);
        // fused expert MLP (both layers, h1 stays in LDS) -> embb bf16
        expert_fused<<<dim3((BCo / 128) * 16), 256, 0, stream>>>(
            xb, W1t, eb1, W2t, eb2, embb);
        // agg -> aggb bf16 [3][BCo][256]
        agg_kernel<<<BCo / 8, 256, 0, stream>>>(embb, gw, aggb, BCo);
        // towers (MFMA, fused both layers) -> out fp32
        tower_fused<<<dim3(BCo / 128, 3), 256, 0, stream>>>(
            aggb, BCo, TW1t, tb1, TW2t, tb2, outc);
    }
}

// Round 6
// 560.673 us; speedup vs baseline: 1.8572x; 1.0579x over previous
//
#include <hip/hip_runtime.h>
#include <math.h>

// Problem constants (fixed by the reference)
#define B_N  16384
#define T_N  3
#define D_N  512
#define G_N  4
#define NE_N 4
#define H_N  512
#define E_N  256
#define GH_N 256
#define K16  16      // G*NE experts
#define TH_N 128
#define TO_N 64

typedef __attribute__((ext_vector_type(8))) short short8;
typedef __attribute__((ext_vector_type(4))) float floatx4;

__device__ __forceinline__ unsigned short f2bf(float f) {
    union { float f; unsigned u; } v; v.f = f;
    unsigned r = (v.u + 0x7fffu + ((v.u >> 16) & 1u)) >> 16;
    return (unsigned short)r;
}
__device__ __forceinline__ float bf2f(unsigned short h) {
    union { unsigned u; float f; } v; v.u = ((unsigned)h) << 16;
    return v.f;
}
__device__ __forceinline__ unsigned pack2(float lo, float hi) {
    return ((unsigned)f2bf(hi) << 16) | (unsigned)f2bf(lo);
}

typedef const __attribute__((address_space(1))) void gvoid_t;
typedef __attribute__((address_space(3))) void lvoid_t;

#if __has_builtin(__builtin_amdgcn_global_load_lds)
#define HAVE_GLL 1
__device__ __forceinline__ void load_lds16(const void* g, void* l) {
    __builtin_amdgcn_global_load_lds((gvoid_t*)g, (lvoid_t*)l, 16, 0, 0);
}
#else
#define HAVE_GLL 0
#endif

// ---------------------------------------------------------------------------
// Input cast: x -> bf16 [BC][G*D]; gin = x[:,1+t]+x[:,0] -> bf16 [BC][T*D]
// (standalone version, used only when the batch is chunked: n_o > 1)
// ---------------------------------------------------------------------------
__global__ __launch_bounds__(256) void convert_inputs(
    const float* __restrict__ x, unsigned short* __restrict__ xb,
    unsigned short* __restrict__ ginb)
{
    const long b = blockIdx.x;
    const int tid = threadIdx.x;           // 256 threads, 2 floats each per g
    const float* xr = x + b * (G_N * D_N);
    unsigned short* xo = xb + b * (G_N * D_N);
    unsigned short* go = ginb + b * (T_N * D_N);
    float2 v0 = *(const float2*)&xr[tid * 2];
    *(unsigned*)&xo[tid * 2] = pack2(v0.x, v0.y);
    #pragma unroll
    for (int g = 1; g < G_N; ++g) {
        float2 v = *(const float2*)&xr[g * D_N + tid * 2];
        *(unsigned*)&xo[g * D_N + tid * 2] = pack2(v.x, v.y);
        *(unsigned*)&go[(g - 1) * D_N + tid * 2] = pack2(v.x + v0.x, v.y + v0.y);
    }
}

// ---------------------------------------------------------------------------
// prep_kernel: ALL weight transposes (5 matrices, 6648 tiles) + input convert
// (nconv rows) in ONE launch.  1-D grid, segment decoded from blockIdx.x.
// ---------------------------------------------------------------------------
__global__ __launch_bounds__(256) void prep_kernel(
    const float* __restrict__ eW1, const float* __restrict__ eW2,
    const float* __restrict__ gW1, const float* __restrict__ tW1,
    const float* __restrict__ tW2,
    unsigned short* __restrict__ W1t, unsigned short* __restrict__ W2t,
    unsigned short* __restrict__ G1t, unsigned short* __restrict__ TW1t,
    unsigned short* __restrict__ TW2t,
    const float* __restrict__ x, unsigned short* __restrict__ xb,
    unsigned short* __restrict__ ginb)
{
    const int bid = blockIdx.x;
    if (bid < 6648) {
        const float* in; unsigned short* out; int K, N, nx, local;
        if (bid < 4096)      { in = eW1; out = W1t;  K = 512; N = 512; nx = 16; local = bid; }
        else if (bid < 6144) { in = eW2; out = W2t;  K = 512; N = 256; nx = 8;  local = bid - 4096; }
        else if (bid < 6528) { in = gW1; out = G1t;  K = 512; N = 256; nx = 8;  local = bid - 6144; }
        else if (bid < 6624) { in = tW1; out = TW1t; K = 256; N = 128; nx = 4;  local = bid - 6528; }
        else                 { in = tW2; out = TW2t; K = 128; N = 64;  nx = 2;  local = bid - 6624; }
        const int ny = K / 32;
        const int xt = local % nx;
        const int yt = (local / nx) % ny;
        const int z  = local / (nx * ny);
        __shared__ float tile[32][33];
        const int tx = threadIdx.x & 31, ty = threadIdx.x >> 5;   // (32,8)
        const long zo = (long)z * K * N;
        const int n0 = xt * 32, k0 = yt * 32;
        #pragma unroll
        for (int i = 0; i < 4; ++i)
            tile[ty + 8 * i][tx] = in[zo + (long)(k0 + ty + 8 * i) * N + n0 + tx];
        __syncthreads();
        #pragma unroll
        for (int i = 0; i < 4; ++i)
            out[zo + (long)(n0 + ty + 8 * i) * K + k0 + tx] = f2bf(tile[tx][ty + 8 * i]);
    } else {
        const long b = bid - 6648;
        const int tid = threadIdx.x;
        const float* xr = x + b * (G_N * D_N);
        unsigned short* xo = xb + b * (G_N * D_N);
        unsigned short* go = ginb + b * (T_N * D_N);
        float2 v0 = *(const float2*)&xr[tid * 2];
        *(unsigned*)&xo[tid * 2] = pack2(v0.x, v0.y);
        #pragma unroll
        for (int g = 1; g < G_N; ++g) {
            float2 v = *(const float2*)&xr[g * D_N + tid * 2];
            *(unsigned*)&xo[g * D_N + tid * 2] = pack2(v.x, v.y);
            *(unsigned*)&go[(g - 1) * D_N + tid * 2] = pack2(v.x + v0.x, v.y + v0.y);
        }
    }
}

// ---------------------------------------------------------------------------
// gate_fused: per block = 128 rows x task t.  Fuses:
//   gh  = relu(gin @ G1_t + gb1)      (MFMA, 2 x 128-col passes -> LDS)
//   lg  = gh @ gW2_t + gb2            (MFMA, W2^T cast to LDS)
//   gw  = softmax_16(lg)              (16-lane shfl reduce)
// Eliminates the gh HBM round-trip and the gate2_softmax kernel.
// LDS: staging 16 KB + ghs 64 KB (XOR-swizzled, granule^=(row&7)) = 80 KB
// -> 2 blocks/CU.  ~130 VGPR (acc[4][4] only).
// ---------------------------------------------------------------------------
__global__ __launch_bounds__(256) void gate_fused(
    const unsigned short* __restrict__ ginb,   // [BC][1536] bf16
    const unsigned short* __restrict__ G1t,    // [3][256][512] bf16 (N-major)
    const float* __restrict__ gb1,             // [3][256]
    const float* __restrict__ gW2,             // [3][256][16] fp32
    const float* __restrict__ gb2,             // [3][16]
    float* __restrict__ gw)                    // [BC][3][16] fp32
{
    __shared__ __align__(16) unsigned short sm[40960];   // 81920 B
    unsigned short* As  = sm;            // [64*32] x2 rows-halves (8 KB)
    unsigned short* Bs  = sm + 4096;     // [128*32]               (8 KB)
    unsigned short* w2s = sm;            // [16][264] (8.4 KB, reuses As+Bs)
    unsigned short* ghs = sm + 8192;     // [128][256] swizzled    (64 KB)

    const int tid = threadIdx.x;
    const int t = blockIdx.y;
    const long b0 = (long)blockIdx.x * 128;
    const unsigned short* Ab = ginb + b0 * 1536 + (long)t * 512;

    const int lane16 = tid & 15;
    const int quad = (tid & 63) >> 4;
    const int wave = tid >> 6;
    const int wm = (wave >> 1) * 64;
    const int wn = (wave & 1) * 64;
    const int srow = tid >> 2;
    const int scol = (((tid & 3) ^ ((tid >> 3) & 3)) * 8);
    const int cw8 = ((quad ^ ((lane16 >> 1) & 3)) * 8);

    #pragma unroll
    for (int ncc = 0; ncc < 2; ++ncc) {
        const unsigned short* Bb = G1t + (long)t * 131072 + (long)(ncc * 128) * 512;
        floatx4 acc[4][4] = {};
        for (int k0 = 0; k0 < 512; k0 += 32) {
#if HAVE_GLL
            load_lds16(Ab + (long)srow * 1536 + k0 + scol, &As[tid * 8]);
            load_lds16(Ab + (long)(srow + 64) * 1536 + k0 + scol, &As[2048 + tid * 8]);
            load_lds16(Bb + (long)srow * 512 + k0 + scol, &Bs[tid * 8]);
            load_lds16(Bb + (long)(srow + 64) * 512 + k0 + scol, &Bs[2048 + tid * 8]);
#else
            *(uint4*)&As[tid * 8] = *(const uint4*)(Ab + (long)srow * 1536 + k0 + scol);
            *(uint4*)&As[2048 + tid * 8] = *(const uint4*)(Ab + (long)(srow + 64) * 1536 + k0 + scol);
            *(uint4*)&Bs[tid * 8] = *(const uint4*)(Bb + (long)srow * 512 + k0 + scol);
            *(uint4*)&Bs[2048 + tid * 8] = *(const uint4*)(Bb + (long)(srow + 64) * 512 + k0 + scol);
#endif
            __syncthreads();
            short8 a[4], b[4];
            #pragma unroll
            for (int mi = 0; mi < 4; ++mi)
                a[mi] = *(const short8*)&As[(wm + mi * 16 + lane16) * 32 + cw8];
            #pragma unroll
            for (int ni = 0; ni < 4; ++ni)
                b[ni] = *(const short8*)&Bs[(wn + ni * 16 + lane16) * 32 + cw8];
            #pragma unroll
            for (int mi = 0; mi < 4; ++mi)
                #pragma unroll
                for (int ni = 0; ni < 4; ++ni)
                    acc[mi][ni] = __builtin_amdgcn_mfma_f32_16x16x32_bf16(
                        a[mi], b[ni], acc[mi][ni], 0, 0, 0);
            __syncthreads();
        }
        // gh epilogue -> swizzled LDS: phys granule = (col>>3) ^ (row&7)
        #pragma unroll
        for (int mi = 0; mi < 4; ++mi) {
            #pragma unroll
            for (int ni = 0; ni < 4; ++ni) {
                const int col = ncc * 128 + wn + ni * 16 + lane16;
                const float bv = gb1[t * GH_N + col];
                #pragma unroll
                for (int r = 0; r < 4; ++r) {
                    const int row = wm + mi * 16 + quad * 4 + r;
                    const int pc = (col & 7) | ((((col >> 3) ^ (row & 7))) << 3);
                    ghs[row * 256 + pc] = f2bf(fmaxf(acc[mi][ni][r] + bv, 0.0f));
                }
            }
        }
    }
    // stage W2^T (fp32 -> bf16) into the dead staging region: w2s[n][k]
    {
        const float* W2p = gW2 + (long)t * (GH_N * K16);
        #pragma unroll
        for (int j = 0; j < 16; ++j)        // n = j, k = tid
            w2s[j * 264 + tid] = f2bf(W2p[(long)tid * K16 + j]);
    }
    __syncthreads();

    // gate2: lg[128][16] = ghs @ w2s^T  (each wave: rows wave*32..+32)
    floatx4 ag[2] = {};
    #pragma unroll
    for (int kk = 0; kk < 8; ++kk) {
        short8 bfr = *(const short8*)&w2s[lane16 * 264 + kk * 32 + quad * 8];
        #pragma unroll
        for (int mi = 0; mi < 2; ++mi) {
            const int row = wave * 32 + mi * 16 + lane16;
            short8 afr = *(const short8*)&ghs[row * 256 + (((kk * 4 + quad) ^ (row & 7)) << 3)];
            ag[mi] = __builtin_amdgcn_mfma_f32_16x16x32_bf16(afr, bfr, ag[mi], 0, 0, 0);
        }
    }

    // softmax over the 16 n-lanes, then store gw
    const float bb2 = gb2[t * K16 + lane16];
    #pragma unroll
    for (int mi = 0; mi < 2; ++mi) {
        float v[4], m = -1e30f;
        #pragma unroll
        for (int r = 0; r < 4; ++r) { v[r] = ag[mi][r] + bb2; }
        #pragma unroll
        for (int r = 0; r < 4; ++r) {
            float mv = v[r];
            #pragma unroll
            for (int d = 1; d < 16; d <<= 1) mv = fmaxf(mv, __shfl_xor(mv, d));
            float e = expf(v[r] - mv);
            float s = e;
            #pragma unroll
            for (int d = 1; d < 16; d <<= 1) s += __shfl_xor(s, d);
            const int row = wave * 32 + mi * 16 + quad * 4 + r;
            gw[(b0 + row) * (T_N * K16) + (long)t * K16 + lane16] = e / s;
        }
    }
}

// ---------------------------------------------------------------------------
// Fused expert MLP (v1, harness-verified @276us): per block = 128 rows x 1
// expert e.  emb[rows,0:256] = relu(x_g @ W1_e) @ W2_e + b2, K-blocked over H
// in 4 chunks of 128; h1 chunk stays in LDS (never touches HBM).
// LDS: 32 KB staging + 34.8 KB h1 = 67.6 KB (2 blocks/CU).  Register floor
// acc2(128 f32)+acc(64 f32) pins this kernel at 2 waves/SIMD — do NOT raise
// the launch_bounds occupancy arg (round-4: (256,3) spilled accs to scratch,
// WRITE 131MB->1.16GB, 276->713us).
// XCD swizzle: experts {2j,2j+1} pinned to XCD j; weight set 1.5 MB/XCD
// stays L2-resident.
// ---------------------------------------------------------------------------
__global__ __launch_bounds__(256, 2) void expert_fused(
    const unsigned short* __restrict__ xb,      // [BC][2048] bf16
    const unsigned short* __restrict__ W1t,     // [16][512][512] bf16 (N-major)
    const float* __restrict__ eb1,              // [16][512]
    const unsigned short* __restrict__ W2t,     // [16][256][512] bf16 (N-major)
    const float* __restrict__ eb2,              // [16][256]
    unsigned short* __restrict__ embb)          // [BC][16*256] bf16
{
    __shared__ __align__(16) unsigned short sm[33792];   // 67584 B
    unsigned short* As  = sm;            // [2][4096]  (stage-1 A / stage-2 W2 tile)
    unsigned short* Bs  = sm + 8192;     // [2][4096]  (stage-1 W1 tile)
    unsigned short* h1s = sm + 16384;    // [128][136] (h1 chunk, padded)

    const int tid = threadIdx.x;
    const unsigned bid = blockIdx.x;
    // XCD-aware swizzle: bid%8 -> XCD (round-robin dispatch); expert pair per XCD
    const int e = ((bid & 7) << 1) | ((bid >> 3) & 1);
    const long m0 = (long)(bid >> 4) * 128;
    const int g = e >> 2;

    const unsigned short* Ab  = xb + m0 * 2048 + g * 512;    // row stride 2048
    const unsigned short* W1b = W1t + (long)e * (512 * 512);
    const unsigned short* W2b = W2t + (long)e * (256 * 512);

    const int lane16 = tid & 15;
    const int quad = (tid & 63) >> 4;
    const int wave = tid >> 6;
    const int wm  = (wave >> 1) * 64;    // row-block of this wave
    const int wn  = (wave & 1) * 64;     // stage-1 col-block
    const int wn2 = (wave & 1) * 128;    // stage-2 col-block
    const int srow = tid >> 2;
    const int scolsw = (((tid & 3) ^ ((tid >> 3) & 3)) * 8);
    const int cw8 = ((quad ^ ((lane16 >> 1) & 3)) * 8);

    floatx4 acc2[4][8] = {};             // emb accumulator (persists all chunks)

    for (int nc = 0; nc < 4; ++nc) {
        const unsigned short* Bb = W1b + ((long)nc << 16);   // nc*128*512
        floatx4 acc[4][4] = {};
        // ---- stage 1: h1c = relu(x @ W1[:, nc*128 : +128]) --------------
        for (int k0 = 0; k0 < 512; k0 += 64) {
            #pragma unroll
            for (int h = 0; h < 2; ++h) {
                const int kh = k0 + h * 32;
#if HAVE_GLL
                load_lds16(Ab + (long)srow * 2048 + kh + scolsw, &As[h * 4096 + tid * 8]);
                load_lds16(Ab + (long)(srow + 64) * 2048 + kh + scolsw, &As[h * 4096 + 2048 + tid * 8]);
                load_lds16(Bb + (long)srow * 512 + kh + scolsw, &Bs[h * 4096 + tid * 8]);
                load_lds16(Bb + (long)(srow + 64) * 512 + kh + scolsw, &Bs[h * 4096 + 2048 + tid * 8]);
#else
                *(uint4*)&As[h * 4096 + tid * 8] = *(const uint4*)(Ab + (long)srow * 2048 + kh + scolsw);
                *(uint4*)&As[h * 4096 + 2048 + tid * 8] = *(const uint4*)(Ab + (long)(srow + 64) * 2048 + kh + scolsw);
                *(uint4*)&Bs[h * 4096 + tid * 8] = *(const uint4*)(Bb + (long)srow * 512 + kh + scolsw);
                *(uint4*)&Bs[h * 4096 + 2048 + tid * 8] = *(const uint4*)(Bb + (long)(srow + 64) * 512 + kh + scolsw);
#endif
            }
            __syncthreads();
            #pragma unroll
            for (int h = 0; h < 2; ++h) {
                short8 b[4];
                #pragma unroll
                for (int ni = 0; ni < 4; ++ni)
                    b[ni] = *(const short8*)&Bs[h * 4096 + (wn + ni * 16 + lane16) * 32 + cw8];
                #pragma unroll
                for (int mi = 0; mi < 4; ++mi) {
                    short8 a = *(const short8*)&As[h * 4096 + (wm + mi * 16 + lane16) * 32 + cw8];
                    #pragma unroll
                    for (int ni = 0; ni < 4; ++ni)
                        acc[mi][ni] = __builtin_amdgcn_mfma_f32_16x16x32_bf16(
                            a, b[ni], acc[mi][ni], 0, 0, 0);
                }
            }
            __syncthreads();
        }
        // ---- h1 epilogue -> LDS (bf16, stride 136: 2-way banks only) ----
        #pragma unroll
        for (int mi = 0; mi < 4; ++mi) {
            #pragma unroll
            for (int ni = 0; ni < 4; ++ni) {
                const int col = wn + ni * 16 + lane16;
                const float bv = eb1[e * 512 + nc * 128 + col];
                #pragma unroll
                for (int r = 0; r < 4; ++r) {
                    const int row = wm + mi * 16 + quad * 4 + r;
                    h1s[row * 136 + col] = f2bf(fmaxf(acc[mi][ni][r] + bv, 0.0f));
                }
            }
        }
        __syncthreads();
        // ---- stage 2: acc2 += h1c @ W2[nc*128:+128, :] -------------------
        #pragma unroll
        for (int ks = 0; ks < 128; ks += 32) {
            #pragma unroll
            for (int i = 0; i < 4; ++i) {
#if HAVE_GLL
                load_lds16(W2b + (long)(srow + 64 * i) * 512 + nc * 128 + ks + scolsw,
                           &As[i * 2048 + tid * 8]);
#else
                *(uint4*)&As[i * 2048 + tid * 8] =
                    *(const uint4*)(W2b + (long)(srow + 64 * i) * 512 + nc * 128 + ks + scolsw);
#endif
            }
            __syncthreads();
            #pragma unroll
            for (int nh = 0; nh < 2; ++nh) {
                short8 b2[4];
                #pragma unroll
                for (int nj = 0; nj < 4; ++nj)
                    b2[nj] = *(const short8*)&As[(wn2 + nh * 64 + nj * 16 + lane16) * 32 + cw8];
                #pragma unroll
                for (int mi = 0; mi < 4; ++mi) {
                    short8 a2 = *(const short8*)&h1s[(wm + mi * 16 + lane16) * 136 + ks + quad * 8];
                    #pragma unroll
                    for (int nj = 0; nj < 4; ++nj)
                        acc2[mi][nh * 4 + nj] = __builtin_amdgcn_mfma_f32_16x16x32_bf16(
                            a2, b2[nj], acc2[mi][nh * 4 + nj], 0, 0, 0);
                }
            }
            __syncthreads();
        }
    }

    // ---- final epilogue: emb -> bf16 embb -------------------------------
    unsigned short* Cb = embb + m0 * 4096 + (long)e * 256;
    #pragma unroll
    for (int mi = 0; mi < 4; ++mi) {
        #pragma unroll
        for (int j = 0; j < 8; ++j) {
            const int col = wn2 + (j >> 2) * 64 + (j & 3) * 16 + lane16;
            const float bv = eb2[e * 256 + col];
            #pragma unroll
            for (int r = 0; r < 4; ++r) {
                const int row = wm + mi * 16 + quad * 4 + r;
                Cb[(long)row * 4096 + col] = f2bf(acc2[mi][j][r] + bv);
            }
        }
    }
}

// ---------------------------------------------------------------------------
// agg: aggb[t][b][e] = bf16( sum_k gw[b][t][k] * emb[b][k*256+e] )
// ---------------------------------------------------------------------------
__global__ __launch_bounds__(256) void agg_kernel(
    const unsigned short* __restrict__ emb, const float* __restrict__ gw,
    unsigned short* __restrict__ aggb, long bc)
{
    const long b = (long)blockIdx.x * 8 + (threadIdx.x >> 5);
    const int e0 = (threadIdx.x & 31) * 8;
    const unsigned short* er = emb + b * 4096 + e0;
    const float* gwr = gw + b * 48;
    float a0[8] = {}, a1[8] = {}, a2[8] = {};
    #pragma unroll
    for (int k = 0; k < 16; ++k) {
        short8 v = *(const short8*)(er + (long)k * 256);
        const float w0 = gwr[k], w1 = gwr[16 + k], w2 = gwr[32 + k];
        #pragma unroll
        for (int j = 0; j < 8; ++j) {
            float f = bf2f((unsigned short)v[j]);
            a0[j] += w0 * f; a1[j] += w1 * f; a2[j] += w2 * f;
        }
    }
    unsigned r0[4] = {pack2(a0[0], a0[1]), pack2(a0[2], a0[3]),
                      pack2(a0[4], a0[5]), pack2(a0[6], a0[7])};
    unsigned r1[4] = {pack2(a1[0], a1[1]), pack2(a1[2], a1[3]),
                      pack2(a1[4], a1[5]), pack2(a1[6], a1[7])};
    unsigned r2[4] = {pack2(a2[0], a2[1]), pack2(a2[2], a2[3]),
                      pack2(a2[4], a2[5]), pack2(a2[6], a2[7])};
    *(uint4*)(aggb + 0L * bc * 256 + b * 256 + e0) = *(uint4*)r0;
    *(uint4*)(aggb + 1L * bc * 256 + b * 256 + e0) = *(uint4*)r1;
    *(uint4*)(aggb + 2L * bc * 256 + b * 256 + e0) = *(uint4*)r2;
}

// ---------------------------------------------------------------------------
// tower_fused (per t): th = relu(agg·W1+b1) [MFMA], out = th·W2+b2 [MFMA]
// ---------------------------------------------------------------------------
__global__ __launch_bounds__(256) void tower_fused(
    const unsigned short* __restrict__ aggb, long bc,
    const unsigned short* __restrict__ w1t, const float* __restrict__ tb1,
    const unsigned short* __restrict__ w2t, const float* __restrict__ tb2,
    float* __restrict__ out)
{
    __shared__ __align__(16) unsigned short sm[26112];   // 52224 B
    unsigned short* As  = sm;            // [128*32]   (stage 1 staging)
    unsigned short* Bs  = sm + 4096;     // [128*32]
    unsigned short* th  = sm;            // [128*136]  (reused after stage 1)
    unsigned short* w2s = sm + 17408;    // [64*136]
    const int tid = threadIdx.x;
    const int t = blockIdx.y;
    const long m0 = (long)blockIdx.x * 128;
    const unsigned short* Ab = aggb + (long)t * bc * 256 + m0 * 256;
    const unsigned short* Bb = w1t + (long)t * (TH_N * E_N);
    const int lane16 = tid & 15;
    const int quad = (tid & 63) >> 4;
    const int wave = tid >> 6;
    const int wm = (wave >> 1) * 64;
    const int wn = (wave & 1) * 64;
    const int srow = tid >> 2;
    const int scolsw = (((tid & 3) ^ ((tid >> 3) & 3)) * 8);
    const int cw8 = ((quad ^ ((lane16 >> 1) & 3)) * 8);

    // W2 tile [64][128] bf16 -> padded w2s [64][136]
    #pragma unroll
    for (int i = 0; i < 4; ++i) {
        const int seg = i * 256 + tid;
        const int row = seg >> 4, cb = (seg & 15) * 8;
        *(uint4*)&w2s[row * 136 + cb] =
            *(const uint4*)&w2t[(long)t * (TO_N * TH_N) + (long)row * 128 + cb];
    }

    floatx4 acc[4][4] = {};
    for (int k0 = 0; k0 < 256; k0 += 32) {
#if HAVE_GLL
        load_lds16(Ab + (long)srow * 256 + k0 + scolsw, &As[tid * 8]);
        load_lds16(Ab + (long)(srow + 64) * 256 + k0 + scolsw, &As[2048 + tid * 8]);
        load_lds16(Bb + (long)srow * 256 + k0 + scolsw, &Bs[tid * 8]);
        load_lds16(Bb + (long)(srow + 64) * 256 + k0 + scolsw, &Bs[2048 + tid * 8]);
#else
        *(uint4*)&As[tid * 8] = *(const uint4*)(Ab + (long)srow * 256 + k0 + scolsw);
        *(uint4*)&As[2048 + tid * 8] = *(const uint4*)(Ab + (long)(srow + 64) * 256 + k0 + scolsw);
        *(uint4*)&Bs[tid * 8] = *(const uint4*)(Bb + (long)srow * 256 + k0 + scolsw);
        *(uint4*)&Bs[2048 + tid * 8] = *(const uint4*)(Bb + (long)(srow + 64) * 256 + k0 + scolsw);
#endif
        __syncthreads();
        short8 a[4], b[4];
        #pragma unroll
        for (int mi = 0; mi < 4; ++mi)
            a[mi] = *(const short8*)&As[(wm + mi * 16 + lane16) * 32 + cw8];
        #pragma unroll
        for (int ni = 0; ni < 4; ++ni)
            b[ni] = *(const short8*)&Bs[(wn + ni * 16 + lane16) * 32 + cw8];
        #pragma unroll
        for (int mi = 0; mi < 4; ++mi)
            #pragma unroll
            for (int ni = 0; ni < 4; ++ni)
                acc[mi][ni] = __builtin_amdgcn_mfma_f32_16x16x32_bf16(
                    a[mi], b[ni], acc[mi][ni], 0, 0, 0);
        __syncthreads();
    }

    #pragma unroll
    for (int mi = 0; mi < 4; ++mi) {
        #pragma unroll
        for (int ni = 0; ni < 4; ++ni) {
            const int col = wn + ni * 16 + lane16;
            const float bv = tb1[t * TH_N + col];
            #pragma unroll
            for (int r = 0; r < 4; ++r) {
                const int row = wm + mi * 16 + quad * 4 + r;
                th[row * 136 + col] = f2bf(fmaxf(acc[mi][ni][r] + bv, 0.0f));
            }
        }
    }
    __syncthreads();

    floatx4 acc2[2][4] = {};
    #pragma unroll
    for (int kk = 0; kk < 4; ++kk) {
        short8 a2[2], b2[4];
        #pragma unroll
        for (int mi = 0; mi < 2; ++mi)
            a2[mi] = *(const short8*)&th[(wave * 32 + mi * 16 + lane16) * 136 + kk * 32 + quad * 8];
        #pragma unroll
        for (int ni = 0; ni < 4; ++ni)
            b2[ni] = *(const short8*)&w2s[(ni * 16 + lane16) * 136 + kk * 32 + quad * 8];
        #pragma unroll
        for (int mi = 0; mi < 2; ++mi)
            #pragma unroll
            for (int ni = 0; ni < 4; ++ni)
                acc2[mi][ni] = __builtin_amdgcn_mfma_f32_16x16x32_bf16(
                    a2[mi], b2[ni], acc2[mi][ni], 0, 0, 0);
    }
    #pragma unroll
    for (int mi = 0; mi < 2; ++mi) {
        #pragma unroll
        for (int ni = 0; ni < 4; ++ni) {
            const int col = ni * 16 + lane16;
            const float bv = tb2[t * TO_N + col];
            #pragma unroll
            for (int r = 0; r < 4; ++r) {
                const int row = wave * 32 + mi * 16 + quad * 4 + r;
                out[(m0 + row) * (T_N * TO_N) + t * TO_N + col] = acc2[mi][ni][r] + bv;
            }
        }
    }
}

// ---------------------------------------------------------------------------
extern "C" void kernel_launch(void* const* d_in, const int* in_sizes, int n_in,
                              void* d_out, int out_size, void* d_ws, size_t ws_size,
                              hipStream_t stream)
{
    const float* x   = (const float*)d_in[0];
    const float* eW1 = (const float*)d_in[1];
    const float* eb1 = (const float*)d_in[2];
    const float* eW2 = (const float*)d_in[3];
    const float* eb2 = (const float*)d_in[4];
    const float* gW1 = (const float*)d_in[5];
    const float* gb1 = (const float*)d_in[6];
    const float* gW2 = (const float*)d_in[7];
    const float* gb2 = (const float*)d_in[8];
    const float* tW1 = (const float*)d_in[9];
    const float* tb1 = (const float*)d_in[10];
    const float* tW2 = (const float*)d_in[11];
    const float* tb2 = (const float*)d_in[12];
    float* out = (float*)d_out;

    char* ws = (char*)d_ws;
    // Persistent weight buffers (bf16, transposed): 13,615,104 B total
    unsigned short* W1t  = (unsigned short*)(ws + 0);          // [16][512][512]
    unsigned short* W2t  = (unsigned short*)(ws + 8388608);    // [16][256][512]
    unsigned short* G1t  = (unsigned short*)(ws + 12582912);   // [3][256][512]
    unsigned short* TW1t = (unsigned short*)(ws + 13369344);   // [3][128][256]
    unsigned short* TW2t = (unsigned short*)(ws + 13565952);   // [3][64][128]
    const size_t WFIX = 13615104;

    // Row-chunk sizing: 18,624 B per row of per-chunk buffers.
    long BCo = 0;
    for (long co = 16384; co >= 128; co >>= 1)
        if (WFIX + (size_t)co * 18624 <= ws_size) { BCo = co; break; }
    if (BCo == 0) return;  // workspace too small — fail cleanly

    char* p = ws + WFIX;
    unsigned short* xb   = (unsigned short*)p; p += BCo * 4096;  // [BCo][G*D]
    unsigned short* ginb = (unsigned short*)p; p += BCo * 3072;  // [BCo][T*D]
    unsigned short* embb = (unsigned short*)p; p += BCo * 8192;  // [BCo][16*E]
    unsigned short* gh   = (unsigned short*)p; p += BCo * 1536;  // (unused, kept for layout)
    float*          gw   = (float*)p;          p += BCo * 192;   // [BCo][T][16]
    unsigned short* aggb = (unsigned short*)p;                   // [3][BCo][256]
    (void)gh;

    const long n_o = B_N / BCo;

    // One launch: all 5 weight transposes (+ input convert when unchunked)
    const long nconv = (n_o == 1) ? BCo : 0;
    prep_kernel<<<dim3((unsigned)(6648 + nconv)), 256, 0, stream>>>(
        eW1, eW2, gW1, tW1, tW2, W1t, W2t, G1t, TW1t, TW2t, x, xb, ginb);

    for (long c = 0; c < n_o; ++c) {
        const float* xc = x + c * BCo * (G_N * D_N);
        float* outc = out + c * BCo * (T_N * TO_N);

        if (n_o > 1)
            convert_inputs<<<BCo, 256, 0, stream>>>(xc, xb, ginb);
        // fused gates: gh (LDS-only) -> softmax weights gw (fp32)
        gate_fused<<<dim3(BCo / 128, 3), 256, 0, stream>>>(
            ginb, G1t, gb1, gW2, gb2, gw);
        // fused expert MLP (both layers, h1 stays in LDS) -> embb bf16
        expert_fused<<<dim3((BCo / 128) * 16), 256, 0, stream>>>(
            xb, W1t, eb1, W2t, eb2, embb);
        // agg -> aggb bf16 [3][BCo][256]
        agg_kernel<<<BCo / 8, 256, 0, stream>>>(embb, gw, aggb, BCo);
        // towers (MFMA, fused both layers) -> out fp32
        tower_fused<<<dim3(BCo / 128, 3), 256, 0, stream>>>(
            aggb, BCo, TW1t, tb1, TW2t, tb2, outc);
    }
}